// Round 7
// baseline (248.346 us; speedup 1.0000x reference)
//
#include <hip/hip_runtime.h>
#include <math.h>

#define BB 64
#define SS 512
#define HH 768
#define AA1 100
#define CC1 300

typedef __bf16 bf16x8 __attribute__((ext_vector_type(8)));
typedef float f32x4 __attribute__((ext_vector_type(4)));

// ---------------------------------------------------------------------------
// Prep: B image, chunk-major per 32-K tile (zero-pad j>=100):
//   chunk index g*112 + j  (g = kt*4 + q), element e:
//   w1i[(g*112 + j)*8 + e] = bf16(w1[(kt*32 + q*8 + e)*100 + j])
// Fragment for (kt,q,n,ln) is the 16B chunk at (kt*448 + q*112 + n*16 + ln).
// ---------------------------------------------------------------------------
__global__ __launch_bounds__(256) void k_prep(const float* __restrict__ w1,
                                              __bf16* __restrict__ w1i) {
    int idx = blockIdx.x * 256 + threadIdx.x;   // 86016 = 336*256
    int j = idx % 112;
    int r = idx / 112;
    int e = r & 7, g = r >> 3;
    int k = (g >> 2) * 32 + (g & 3) * 8 + e;
    float v = (j < AA1) ? w1[k * AA1 + j] : 0.f;
    w1i[((size_t)g * 112 + j) * 8 + e] = (__bf16)v;
}

// ---------------------------------------------------------------------------
// Kernel 1: token attention, bf16 MFMA 16x16x32 — direct-to-register, no LDS,
// no barriers. 128 tokens/block (4 waves x 32 tokens), 7 N-tiles, 24 K-iters.
// A loads: 2x16B contiguous per lane (128B contiguous per token row).
// B loads: 16B chunk per lane, 256B contiguous per n-tile; L2-resident.
// ---------------------------------------------------------------------------
__global__ __launch_bounds__(256) void k_token_att(
        const float* __restrict__ hs, const __bf16* __restrict__ w1i,
        const float* __restrict__ b1, const float* __restrict__ w2,
        const float* __restrict__ b2, float* __restrict__ token_att) {
    const int tid = threadIdx.x;
    const int tok0 = blockIdx.x * 128;
    const int w = tid >> 6, lane = tid & 63;
    const int q = lane >> 4, ln = lane & 15;

    const float* pa0 = hs + (size_t)(tok0 + w * 32 + ln) * HH + q * 8;
    const float* pa1 = pa0 + (size_t)16 * HH;
    const __bf16* pb = w1i + ((size_t)q * 112 + ln) * 8;

    f32x4 acc0[7], acc1[7];
#pragma unroll
    for (int n = 0; n < 7; n++) {
        acc0[n] = (f32x4){0.f, 0.f, 0.f, 0.f};
        acc1[n] = (f32x4){0.f, 0.f, 0.f, 0.f};
    }

#pragma unroll 2
    for (int kt = 0; kt < 24; kt++) {
        f32x4 a00 = *(const f32x4*)(pa0 + kt * 32);
        f32x4 a01 = *(const f32x4*)(pa0 + kt * 32 + 4);
        f32x4 a10 = *(const f32x4*)(pa1 + kt * 32);
        f32x4 a11 = *(const f32x4*)(pa1 + kt * 32 + 4);
        bf16x8 bfr[7];
#pragma unroll
        for (int n = 0; n < 7; n++)
            bfr[n] = *(const bf16x8*)(pb + (size_t)kt * 3584 + n * 128);
        bf16x8 af0, af1;
#pragma unroll
        for (int e = 0; e < 4; e++) {
            af0[e] = (__bf16)a00[e]; af0[e + 4] = (__bf16)a01[e];
            af1[e] = (__bf16)a10[e]; af1[e + 4] = (__bf16)a11[e];
        }
#pragma unroll
        for (int n = 0; n < 7; n++) {
            acc0[n] = __builtin_amdgcn_mfma_f32_16x16x32_bf16(af0, bfr[n], acc0[n], 0, 0, 0);
            acc1[n] = __builtin_amdgcn_mfma_f32_16x16x32_bf16(af1, bfr[n], acc1[n], 0, 0, 0);
        }
    }

    // epilogue: C/D layout col j = n*16+ln, token = base + q*4 + reg
    float s0 = 0.f, s1 = 0.f, s2 = 0.f, s3 = 0.f;
    float u0 = 0.f, u1 = 0.f, u2 = 0.f, u3 = 0.f;
#pragma unroll
    for (int n = 0; n < 7; n++) {
        int j = n * 16 + ln;
        if (j < AA1) {
            float bj = b1[j], wj = w2[j];
            s0 += tanhf(acc0[n][0] + bj) * wj;
            s1 += tanhf(acc0[n][1] + bj) * wj;
            s2 += tanhf(acc0[n][2] + bj) * wj;
            s3 += tanhf(acc0[n][3] + bj) * wj;
            u0 += tanhf(acc1[n][0] + bj) * wj;
            u1 += tanhf(acc1[n][1] + bj) * wj;
            u2 += tanhf(acc1[n][2] + bj) * wj;
            u3 += tanhf(acc1[n][3] + bj) * wj;
        }
    }
#pragma unroll
    for (int off = 1; off < 16; off <<= 1) {
        s0 += __shfl_xor(s0, off); s1 += __shfl_xor(s1, off);
        s2 += __shfl_xor(s2, off); s3 += __shfl_xor(s3, off);
        u0 += __shfl_xor(u0, off); u1 += __shfl_xor(u1, off);
        u2 += __shfl_xor(u2, off); u3 += __shfl_xor(u3, off);
    }
    if (ln == 0) {
        float bb = b2[0];
        int base0 = tok0 + w * 32 + q * 4;
        int base1 = base0 + 16;
        token_att[base0 + 0] = 1.f / (1.f + expf(-(s0 + bb)));
        token_att[base0 + 1] = 1.f / (1.f + expf(-(s1 + bb)));
        token_att[base0 + 2] = 1.f / (1.f + expf(-(s2 + bb)));
        token_att[base0 + 3] = 1.f / (1.f + expf(-(s3 + bb)));
        token_att[base1 + 0] = 1.f / (1.f + expf(-(u0 + bb)));
        token_att[base1 + 1] = 1.f / (1.f + expf(-(u1 + bb)));
        token_att[base1 + 2] = 1.f / (1.f + expf(-(u2 + bb)));
        token_att[base1 + 3] = 1.f / (1.f + expf(-(u3 + bb)));
    }
}

// ---------------------------------------------------------------------------
// Kernel 2: scan/segmax/mask + stats + compaction. Also zeroes pooled[b] and
// (block 0) out[0..5) — atomic targets of later dispatches.
// ---------------------------------------------------------------------------
__global__ __launch_bounds__(512) void k_mask(
        const float* __restrict__ token_att, const float* __restrict__ labels,
        const int* __restrict__ offm, float* __restrict__ masked_out,
        float* __restrict__ cw_g, short* __restrict__ cs_g,
        int* __restrict__ nnz_g, float* __restrict__ inv_g,
        float4* __restrict__ stats_g, float* __restrict__ pooled,
        float* __restrict__ out) {
    __shared__ int smax[512];
    __shared__ int wscan[8];
    __shared__ int wscan2[8];
    __shared__ float wred[5][8];

    const int b = blockIdx.x, s = threadIdx.x;
    const int lane = s & 63, wv = s >> 6;
    if (b == 0 && s < 5) out[s] = 0.f;
    pooled[b * HH + s] = 0.f;
    if (s < HH - SS) pooled[b * HH + SS + s] = 0.f;
    const int ns = (offm[(b * SS + s) * 2] == 0) ? 1 : 0;

    int v = ns;
#pragma unroll
    for (int off = 1; off < 64; off <<= 1) {
        int o = __shfl_up(v, off);
        if (lane >= off) v += o;
    }
    if (lane == 63) wscan[wv] = v;
    smax[s] = 0;
    __syncthreads();
    int woff = 0;
    for (int i = 0; i < 8; i++) woff += (i < wv) ? wscan[i] : 0;
    const int seg = max(v + woff - 1, 0);

    const float ta = token_att[b * SS + s];
    atomicMax(&smax[seg], __float_as_int(ta));   // sigmoid > 0: int order ok
    __syncthreads();

    const float wa = ns ? __int_as_float(smax[seg]) : 0.f;
    const float lab = labels[b * SS + s];
    const float m = (lab != -1.f && ns) ? wa : 0.f;
    masked_out[b * SS + s] = m;

    const float zl = (lab != -1.f) ? lab : 0.f;
    const float tl = (m - zl) * (m - zl);
    const float ones = (m == 0.f) ? 1.f : m;

    float r0 = m, r1 = tl, r2 = m, r3 = ones, r4 = lab;
#pragma unroll
    for (int off = 32; off > 0; off >>= 1) {
        r0 += __shfl_xor(r0, off);
        r1 += __shfl_xor(r1, off);
        r2 = fmaxf(r2, __shfl_xor(r2, off));
        r3 = fminf(r3, __shfl_xor(r3, off));
        r4 = fmaxf(r4, __shfl_xor(r4, off));
    }
    if (lane == 0) {
        wred[0][wv] = r0; wred[1][wv] = r1; wred[2][wv] = r2;
        wred[3][wv] = r3; wred[4][wv] = r4;
    }

    const int nz = (m != 0.f) ? 1 : 0;
    int v2 = nz;
#pragma unroll
    for (int off = 1; off < 64; off <<= 1) {
        int o = __shfl_up(v2, off);
        if (lane >= off) v2 += o;
    }
    if (lane == 63) wscan2[wv] = v2;
    __syncthreads();

    int woff2 = 0;
    for (int i = 0; i < 8; i++) woff2 += (i < wv) ? wscan2[i] : 0;
    if (nz) {
        int pos = v2 + woff2 - 1;
        cw_g[b * SS + pos] = m;
        cs_g[b * SS + pos] = (short)s;
    }
    if (s == 0) {
        float att = 0.f, tokl = 0.f, maxm = -1e30f, minone = 1e30f, slab = -1e30f;
        int nnz = 0;
        for (int i = 0; i < 8; i++) {
            att += wred[0][i]; tokl += wred[1][i];
            maxm = fmaxf(maxm, wred[2][i]);
            minone = fminf(minone, wred[3][i]);
            slab = fmaxf(slab, wred[4][i]);
            nnz += wscan2[i];
        }
        nnz_g[b] = nnz;
        inv_g[b] = 1.f / att;
        stats_g[b] = make_float4(tokl, maxm, minone, slab);
    }
}

// ---------------------------------------------------------------------------
// Kernel 3: pooled[b,h] += sum_{i mod 8 == g} cw[i]*hs[b,cs[i],h]
// grid (BB, 8) = 512 blocks; ~11 tokens x 3 h-channels per thread, all loads
// independent; atomicAdd into pooled (zeroed by k_mask).
// ---------------------------------------------------------------------------
__global__ __launch_bounds__(256) void k_pool(
        const float* __restrict__ hs, const float* __restrict__ cw_g,
        const short* __restrict__ cs_g, const int* __restrict__ nnz_g,
        float* __restrict__ pooled) {
    const int b = blockIdx.x, g = blockIdx.y, tid = threadIdx.x;
    const int nnz = nnz_g[b];
    const float* hsb = hs + (size_t)b * SS * HH;
    float a0 = 0.f, a1 = 0.f, a2 = 0.f;
#pragma unroll 2
    for (int i = g; i < nnz; i += 8) {
        const float wv = cw_g[b * SS + i];
        const int s = cs_g[b * SS + i];
        const float* hp = hsb + (size_t)s * HH;
        a0 += hp[tid] * wv;
        a1 += hp[tid + 256] * wv;
        a2 += hp[tid + 512] * wv;
    }
    atomicAdd(&pooled[b * HH + tid], a0);
    atomicAdd(&pooled[b * HH + tid + 256], a1);
    atomicAdd(&pooled[b * HH + tid + 512], a2);
}

// ---------------------------------------------------------------------------
// Kernel 4: sentence MLP + sigmoid + per-row loss atomics.
// One block (320 threads) per row; thread = hidden unit (coalesced over sw1).
// ---------------------------------------------------------------------------
__global__ __launch_bounds__(320) void k_sentfinal(
        const float* __restrict__ pooled, const float* __restrict__ inv_g,
        const float4* __restrict__ stats_g,
        const float* __restrict__ sw1, const float* __restrict__ sb1,
        const float* __restrict__ sw2, const float* __restrict__ sb2,
        float* __restrict__ sent_out, float* __restrict__ out) {
    __shared__ float p[HH];
    __shared__ float wsum[5];
    const int b = blockIdx.x, tid = threadIdx.x;
    const int lane = tid & 63, wv = tid >> 6;
    const float inv = inv_g[b];
    for (int i = tid; i < HH; i += 320) p[i] = pooled[b * HH + i] * inv;
    __syncthreads();

    float tt = 0.f;
    if (tid < CC1) {
        float z = sb1[tid];
#pragma unroll 8
        for (int k = 0; k < HH; k++) z += p[k] * sw1[k * CC1 + tid];
        tt = tanhf(z) * sw2[tid];
    }
#pragma unroll
    for (int off = 32; off > 0; off >>= 1) tt += __shfl_xor(tt, off);
    if (lane == 0) wsum[wv] = tt;
    __syncthreads();
    if (tid == 0) {
        float zsum = wsum[0] + wsum[1] + wsum[2] + wsum[3] + wsum[4];
        float sv = 1.f / (1.f + expf(-(zsum + sb2[0])));
        sent_out[b] = sv;
        float4 st = stats_g[b];             // tokl, maxm, minone, slab
        float vs = sv - st.w; vs *= vs;
        float ra = st.z * st.z;
        float rb = st.y - st.w; rb *= rb;
        atomicAdd(&out[1], vs);
        atomicAdd(&out[2], st.x);
        atomicAdd(&out[3], ra);
        atomicAdd(&out[4], rb);
        atomicAdd(&out[0], vs + st.x + 0.01f * (ra + rb));
    }
}

extern "C" void kernel_launch(void* const* d_in, const int* in_sizes, int n_in,
                              void* d_out, int out_size, void* d_ws, size_t ws_size,
                              hipStream_t stream) {
    const float* hs  = (const float*)d_in[0];
    const float* w1  = (const float*)d_in[1];
    const float* b1  = (const float*)d_in[2];
    const float* w2  = (const float*)d_in[3];
    const float* b2  = (const float*)d_in[4];
    const float* sw1 = (const float*)d_in[5];
    const float* sb1 = (const float*)d_in[6];
    const float* sw2 = (const float*)d_in[7];
    const float* sb2 = (const float*)d_in[8];
    const float* labels = (const float*)d_in[9];
    const int*   offm   = (const int*)d_in[10];

    float* out = (float*)d_out;
    float* ws  = (float*)d_ws;

    // ws layout (float units)
    float*  token_att = ws;                       // 32768
    __bf16* w1i    = (__bf16*)(ws + 32768);       // 86016 bf16 = 43008 f
    float*  cw     = ws + 32768 + 43008;          // 32768
    short*  cs     = (short*)(cw + 32768);        // 32768 shorts = 16384 f
    int*    nnz    = (int*)(cw + 32768 + 16384);  // 64
    float*  inv    = (float*)(nnz + 64);          // 64
    float4* stats  = (float4*)(inv + 64);         // 64 float4 = 256 f
    float*  pooled = inv + 64 + 256;              // 49152

    // d_out layout: [total, sentence_loss, token_loss, reg_a, reg_b,
    //                masked(64*512), sent(64)]
    float* masked_out = out + 5;
    float* sent_out   = out + 5 + BB * SS;

    hipLaunchKernelGGL(k_prep, dim3(336), dim3(256), 0, stream, w1, w1i);
    hipLaunchKernelGGL(k_token_att, dim3(256), dim3(256), 0, stream,
                       hs, w1i, b1, w2, b2, token_att);
    hipLaunchKernelGGL(k_mask, dim3(BB), dim3(512), 0, stream,
                       token_att, labels, offm, masked_out,
                       cw, cs, nnz, inv, stats, pooled, out);
    hipLaunchKernelGGL(k_pool, dim3(BB, 8), dim3(256), 0, stream,
                       hs, cw, cs, nnz, pooled);
    hipLaunchKernelGGL(k_sentfinal, dim3(BB), dim3(320), 0, stream,
                       pooled, inv, stats, sw1, sb1, sw2, sb2, sent_out, out);
}